// Round 1
// baseline (1029.027 us; speedup 1.0000x reference)
//
#include <hip/hip_runtime.h>
#include <cstdint>

#define TOKENS 65536
#define DIM    1024
#define NEXP   64
#define NBLK1  1024   // K1 blocks, 64 tokens each
#define KC     64     // k-chunk per stage
#define TPAD   68     // x tile row stride (floats), 16B-aligned rows
#define XPAD   65     // exchange row stride (odd -> conflict-free)

// ---------------------------------------------------------------------------
// K1: logits GEMM (fp32 vector, expert-split waves) + softmax + top2 + outputs
//     g1,g2,i1,i2 + per-group histograms/ranks + me partials.
// Block: 128 threads = 2 waves. wave w computes experts [32w,32w+32) for the
// block's 64 tokens (lane = token). Grid: 1024 blocks -> 2048 waves = 2/SIMD.
// ---------------------------------------------------------------------------
__global__ __launch_bounds__(128) void k1_gate(
    const float* __restrict__ x, const float* __restrict__ wgm,
    float* __restrict__ out, uint32_t* __restrict__ pack,
    int* __restrict__ h1, int* __restrict__ h2, float* __restrict__ mep)
{
    __shared__ float tile[64 * TPAD];   // 17408 B x-chunk
    __shared__ float xch[64 * XPAD];    // 16640 B exchange/transpose buffer

    const int tid  = threadIdx.x;
    const int lane = tid & 63;
    const int wid  = tid >> 6;
    const int blk  = blockIdx.x;
    const int tok0 = blk * 64;

    float acc[32];
#pragma unroll
    for (int e = 0; e < 32; ++e) acc[e] = 0.f;

    // wave-uniform expert base so wg loads become scalar (s_load) loads
    const int ebase = __builtin_amdgcn_readfirstlane(wid * 32);
    const float* __restrict__ wgw = wgm + (size_t)ebase * DIM;

#pragma unroll 1
    for (int s = 0; s < DIM / KC; ++s) {
        const int kc = s * KC;
        __syncthreads();                 // previous chunk fully consumed
        // cooperative coalesced stage: 64 tokens x 64 cols, 8 float4/thread
#pragma unroll
        for (int p = 0; p < 8; ++p) {
            int flat = p * 128 + tid;    // float4 index in tile
            int row  = flat >> 4;
            int slot = flat & 15;
            const float4 v = *(const float4*)(x + (size_t)(tok0 + row) * DIM + kc + slot * 4);
            *(float4*)(tile + row * TPAD + slot * 4) = v;
        }
        __syncthreads();
#pragma unroll
        for (int kk = 0; kk < KC; kk += 8) {
            const float* xr = tile + lane * TPAD + kk;
            float4 xa = *(const float4*)xr;
            float4 xb = *(const float4*)(xr + 4);
#pragma unroll
            for (int e = 0; e < 32; ++e) {
                const float* w = wgw + (size_t)e * DIM + kc + kk;  // uniform -> SGPR
                float a = acc[e];
                a = fmaf(xa.x, w[0], a);
                a = fmaf(xa.y, w[1], a);
                a = fmaf(xa.z, w[2], a);
                a = fmaf(xa.w, w[3], a);
                a = fmaf(xb.x, w[4], a);
                a = fmaf(xb.y, w[5], a);
                a = fmaf(xb.z, w[6], a);
                a = fmaf(xb.w, w[7], a);
                acc[e] = a;
            }
        }
    }

    // exchange wave1's experts to wave0
    __syncthreads();
    if (wid == 1) {
#pragma unroll
        for (int e = 0; e < 32; ++e) xch[lane * XPAD + e] = acc[e];
    }
    __syncthreads();

    int i1 = 0, i2 = 0;
    if (wid == 0) {
        float z[64];
#pragma unroll
        for (int e = 0; e < 32; ++e) z[e] = acc[e];
#pragma unroll
        for (int e = 0; e < 32; ++e) z[32 + e] = xch[lane * XPAD + e];

        // sequential top-2 (tie semantics match lax.top_k: strict >)
        float m1 = -3.402823466e+38f, m2 = -3.402823466e+38f;
#pragma unroll
        for (int e = 0; e < 64; ++e) {
            float v = z[e];
            if (v > m1)      { m2 = m1; i2 = i1; m1 = v; i1 = e; }
            else if (v > m2) { m2 = v;  i2 = e; }
        }
        float sum = 0.f;
#pragma unroll
        for (int e = 0; e < 64; ++e) { float p = __expf(z[e] - m1); z[e] = p; sum += p; }
        float inv = 1.0f / sum;
        float g1  = inv;                    // exp(0)*inv
        float g2  = __expf(m2 - m1) * inv;
        float den = fmaxf(g1 + g2, 1.1920929e-07f);  // fp32 eps
        float rd  = 1.0f / den;
        const int tok = tok0 + lane;
        out[1 + tok]              = g1 * rd;
        out[1 + TOKENS + tok]     = g2 * rd;
        out[1 + 2 * TOKENS + tok] = (float)i1;
        out[1 + 3 * TOKENS + tok] = (float)i2;
        // normalized gates rows -> LDS for the me column-sum (transpose)
#pragma unroll
        for (int e = 0; e < 64; ++e) xch[lane * XPAD + e] = z[e] * inv;
    }
    __syncthreads();
    if (wid == 0) {
        // me partial: lane l sums expert-l gates over the 64 tokens
        float msum = 0.f;
#pragma unroll
        for (int r = 0; r < 64; ++r) msum += xch[r * XPAD + lane];
        mep[blk * NEXP + lane] = msum;

        // per-group histograms + in-group exclusive ranks via 64-bit ballots
        unsigned long long lt = (1ull << lane) - 1ull;
        int r1 = 0, r2 = 0, myh1 = 0, myh2 = 0;
        for (int e = 0; e < 64; ++e) {
            unsigned long long b1 = __ballot(i1 == e);
            unsigned long long b2 = __ballot(i2 == e);
            if (i1 == e)   r1 = (int)__popcll(b1 & lt);
            if (i2 == e)   r2 = (int)__popcll(b2 & lt);
            if (lane == e) { myh1 = (int)__popcll(b1); myh2 = (int)__popcll(b2); }
        }
        h1[blk * NEXP + lane] = myh1;
        h2[blk * NEXP + lane] = myh2;
        pack[tok0 + lane] = (uint32_t)i1 | ((uint32_t)i2 << 6) |
                            ((uint32_t)r1 << 12) | ((uint32_t)r2 << 18);
    }
}

// ---------------------------------------------------------------------------
// K2: per-expert exclusive scan over the 1024 group histograms (locations
// offsets), ce totals, me reduction, loss partial. One block per expert.
// ---------------------------------------------------------------------------
__global__ __launch_bounds__(256) void k2_scan(
    const int* __restrict__ h1, const int* __restrict__ h2, const float* __restrict__ mep,
    int* __restrict__ off1, int* __restrict__ off2, int* __restrict__ ce,
    float* __restrict__ loss)
{
    const int e = blockIdx.x, t = threadIdx.x;
    __shared__ int   sb[256];
    __shared__ float fb[256];

    // ---- scan h1
    int v0 = h1[(4 * t + 0) * NEXP + e], v1 = h1[(4 * t + 1) * NEXP + e];
    int v2 = h1[(4 * t + 2) * NEXP + e], v3 = h1[(4 * t + 3) * NEXP + e];
    int ts = v0 + v1 + v2 + v3;
    sb[t] = ts; __syncthreads();
    for (int d = 1; d < 256; d <<= 1) {
        int a = (t >= d) ? sb[t - d] : 0;
        __syncthreads();
        sb[t] += a;
        __syncthreads();
    }
    int total1 = sb[255];
    int ex = sb[t] - ts;
    off1[(4 * t + 0) * NEXP + e] = ex;
    off1[(4 * t + 1) * NEXP + e] = ex + v0;
    off1[(4 * t + 2) * NEXP + e] = ex + v0 + v1;
    off1[(4 * t + 3) * NEXP + e] = ex + v0 + v1 + v2;
    if (t == 0) ce[e] = total1;
    __syncthreads();

    // ---- scan h2
    v0 = h2[(4 * t + 0) * NEXP + e]; v1 = h2[(4 * t + 1) * NEXP + e];
    v2 = h2[(4 * t + 2) * NEXP + e]; v3 = h2[(4 * t + 3) * NEXP + e];
    ts = v0 + v1 + v2 + v3;
    sb[t] = ts; __syncthreads();
    for (int d = 1; d < 256; d <<= 1) {
        int a = (t >= d) ? sb[t - d] : 0;
        __syncthreads();
        sb[t] += a;
        __syncthreads();
    }
    ex = sb[t] - ts;
    off2[(4 * t + 0) * NEXP + e] = ex;
    off2[(4 * t + 1) * NEXP + e] = ex + v0;
    off2[(4 * t + 2) * NEXP + e] = ex + v0 + v1;
    off2[(4 * t + 3) * NEXP + e] = ex + v0 + v1 + v2;
    __syncthreads();

    // ---- me reduce + loss partial
    float ms = mep[(4 * t + 0) * NEXP + e] + mep[(4 * t + 1) * NEXP + e] +
               mep[(4 * t + 2) * NEXP + e] + mep[(4 * t + 3) * NEXP + e];
    fb[t] = ms; __syncthreads();
    for (int d = 128; d > 0; d >>= 1) {
        if (t < d) fb[t] += fb[t + d];
        __syncthreads();
    }
    if (t == 0) atomicAdd(loss, fb[0] * (float)total1);
}

// ---------------------------------------------------------------------------
// K3: final locations + loss write.
// ---------------------------------------------------------------------------
__global__ __launch_bounds__(256) void k3_loc(
    const uint32_t* __restrict__ pack, const int* __restrict__ off1,
    const int* __restrict__ off2, const int* __restrict__ ce,
    const float* __restrict__ loss, float* __restrict__ out)
{
    const int sIdx = blockIdx.x * 256 + threadIdx.x;
    uint32_t p = pack[sIdx];
    int i1 = p & 63, i2 = (p >> 6) & 63, r1 = (p >> 12) & 63, r2 = (p >> 18) & 63;
    int g = sIdx >> 6;
    out[1 + 4 * TOKENS + sIdx] = (float)(off1[g * NEXP + i1] + r1);
    out[1 + 5 * TOKENS + sIdx] = (float)(off2[g * NEXP + i2] + r2 + ce[i2]);
    if (sIdx == 0) out[0] = loss[0] * 1.4901161193847656e-08f;  // * E/S^2
}

extern "C" void kernel_launch(void* const* d_in, const int* in_sizes, int n_in,
                              void* d_out, int out_size, void* d_ws, size_t ws_size,
                              hipStream_t stream)
{
    const float* x  = (const float*)d_in[0];   // [65536,1024] fp32
    const float* wg = (const float*)d_in[1];   // [64,1024] fp32
    float* out = (float*)d_out;

    // workspace carve (~1.6 MB)
    char* w = (char*)d_ws;
    uint32_t* pack = (uint32_t*)w; w += (size_t)TOKENS * 4;
    int*   h1   = (int*)w;   w += (size_t)NBLK1 * NEXP * 4;
    int*   h2   = (int*)w;   w += (size_t)NBLK1 * NEXP * 4;
    float* mep  = (float*)w; w += (size_t)NBLK1 * NEXP * 4;
    int*   off1 = (int*)w;   w += (size_t)NBLK1 * NEXP * 4;
    int*   off2 = (int*)w;   w += (size_t)NBLK1 * NEXP * 4;
    int*   ce   = (int*)w;   w += 256;
    float* loss = (float*)w; w += 256;

    hipMemsetAsync(loss, 0, 4, stream);
    k1_gate<<<NBLK1, 128, 0, stream>>>(x, wg, out, pack, h1, h2, mep);
    k2_scan<<<NEXP, 256, 0, stream>>>(h1, h2, mep, off1, off2, ce, loss);
    k3_loc<<<TOKENS / 256, 256, 0, stream>>>(pack, off1, off2, ce, loss, out);
}

// Round 4
// 553.031 us; speedup vs baseline: 1.8607x; 1.8607x over previous
//
#include <hip/hip_runtime.h>
#include <cstdint>

#define TOKENS 65536
#define DIM    1024
#define NEXP   64
#define NBLK1  1024   // K1 blocks, 64 tokens each
#define KC     64     // k-chunk per stage
#define TPAD   68     // x tile row stride (floats), 16B-aligned rows

// ---------------------------------------------------------------------------
// K1: logits GEMM (fp32 vector) + softmax + top2 + outputs.
// Block: 512 threads = 8 waves, 64 tokens (lane = token for every wave).
// Wave w computes experts [8w, 8w+8) -> acc = 8 VGPRs. Grid 1024 blocks ->
// 8192 waves = 8/SIMD at <=64 VGPR -> 100% occupancy (vs 24% in round 1);
// the 8-way TLP hides the wg s_load latency that stalled round 1 (VALUBusy 29%).
// LDS: single 17.4 KB x-tile -> 4 blocks/CU.
// ---------------------------------------------------------------------------
__global__ __launch_bounds__(512, 8) void k1_gate(
    const float* __restrict__ x, const float* __restrict__ wgm,
    float* __restrict__ out, uint32_t* __restrict__ pack,
    int* __restrict__ h1, int* __restrict__ h2, float* __restrict__ mep)
{
    __shared__ float tile[64 * TPAD];   // 17408 B

    const int tid  = threadIdx.x;
    const int lane = tid & 63;
    const int wid  = tid >> 6;          // 0..7
    const int tok0 = blockIdx.x * 64;

    float acc[8];
#pragma unroll
    for (int e = 0; e < 8; ++e) acc[e] = 0.f;

    // wave-uniform expert base so wg reads become scalar (s_load) ops
    const int ebase = __builtin_amdgcn_readfirstlane(wid * 8);
    const float* __restrict__ wgw = wgm + (size_t)ebase * DIM;

#pragma unroll 1
    for (int s = 0; s < DIM / KC; ++s) {
        const int kc = s * KC;
        __syncthreads();                 // previous chunk fully consumed
        // cooperative coalesced stage: 64 tokens x 64 cols, 2 float4/thread
#pragma unroll
        for (int p = 0; p < 2; ++p) {
            const int flat = p * 512 + tid;      // float4 index
            const int row  = flat >> 4;
            const int slot = (flat & 15) * 4;
            *(float4*)(tile + row * TPAD + slot) =
                *(const float4*)(x + (size_t)(tok0 + row) * DIM + kc + slot);
        }
        __syncthreads();
#pragma unroll
        for (int kk = 0; kk < KC; kk += 8) {
            const float4 xa = *(const float4*)(tile + lane * TPAD + kk);
            const float4 xb = *(const float4*)(tile + lane * TPAD + kk + 4);
#pragma unroll
            for (int e = 0; e < 8; ++e) {
                const float* w = wgw + (size_t)e * DIM + kc + kk;  // uniform -> SGPR
                float a = acc[e];
                a = fmaf(xa.x, w[0], a);
                a = fmaf(xa.y, w[1], a);
                a = fmaf(xa.z, w[2], a);
                a = fmaf(xa.w, w[3], a);
                a = fmaf(xb.x, w[4], a);
                a = fmaf(xb.y, w[5], a);
                a = fmaf(xb.z, w[6], a);
                a = fmaf(xb.w, w[7], a);
                acc[e] = a;
            }
        }
    }

    // gather all 64 logits per token into LDS (reuse tile as [64][TPAD])
    __syncthreads();
    *(float4*)(tile + lane * TPAD + ebase)     = make_float4(acc[0], acc[1], acc[2], acc[3]);
    *(float4*)(tile + lane * TPAD + ebase + 4) = make_float4(acc[4], acc[5], acc[6], acc[7]);
    __syncthreads();

    int i1 = 0, i2 = 0;
    if (wid == 0) {
        float* row = tile + lane * TPAD;
        // pass 1: top-2 (strict >, earliest index on ties == stable top_k)
        float m1 = -3.402823466e+38f, m2 = -3.402823466e+38f;
#pragma unroll
        for (int e = 0; e < NEXP; e += 4) {
            const float4 v = *(const float4*)(row + e);
            if (v.x > m1)      { m2 = m1; i2 = i1; m1 = v.x; i1 = e; }
            else if (v.x > m2) { m2 = v.x; i2 = e; }
            if (v.y > m1)      { m2 = m1; i2 = i1; m1 = v.y; i1 = e + 1; }
            else if (v.y > m2) { m2 = v.y; i2 = e + 1; }
            if (v.z > m1)      { m2 = m1; i2 = i1; m1 = v.z; i1 = e + 2; }
            else if (v.z > m2) { m2 = v.z; i2 = e + 2; }
            if (v.w > m1)      { m2 = m1; i2 = i1; m1 = v.w; i1 = e + 3; }
            else if (v.w > m2) { m2 = v.w; i2 = e + 3; }
        }
        // pass 2: exp + sum, overwrite row with p (no z[64] array -> low VGPR)
        float sum = 0.f;
#pragma unroll
        for (int e = 0; e < NEXP; e += 4) {
            float4 v = *(const float4*)(row + e);
            v.x = __expf(v.x - m1);
            v.y = __expf(v.y - m1);
            v.z = __expf(v.z - m1);
            v.w = __expf(v.w - m1);
            sum += (v.x + v.y) + (v.z + v.w);
            *(float4*)(row + e) = v;
        }
        const float inv = 1.0f / sum;
        row[64] = inv;                       // stash per-token inv for me colsum
        const float g1 = inv;                // exp(0)*inv
        const float g2 = __expf(m2 - m1) * inv;
        const float den = fmaxf(g1 + g2, 1.1920929e-07f);  // fp32 eps
        const float rd  = 1.0f / den;
        const int tok = tok0 + lane;
        out[1 + tok]              = g1 * rd;
        out[1 + TOKENS + tok]     = g2 * rd;
        out[1 + 2 * TOKENS + tok] = (float)i1;
        out[1 + 3 * TOKENS + tok] = (float)i2;
    }
    __syncthreads();
    if (wid == 0) {
        // me partial: lane = expert, sum p*inv down the 64 token rows
        float msum = 0.f;
#pragma unroll 8
        for (int r = 0; r < 64; ++r)
            msum += tile[r * TPAD + lane] * tile[r * TPAD + 64];
        mep[blockIdx.x * NEXP + lane] = msum;

        // per-group histograms + in-group exclusive ranks via 64-bit ballots
        const unsigned long long lt = (1ull << lane) - 1ull;
        int r1 = 0, r2 = 0, myh1 = 0, myh2 = 0;
        for (int e = 0; e < NEXP; ++e) {
            const unsigned long long b1 = __ballot(i1 == e);
            const unsigned long long b2 = __ballot(i2 == e);
            if (i1 == e)   r1 = (int)__popcll(b1 & lt);
            if (i2 == e)   r2 = (int)__popcll(b2 & lt);
            if (lane == e) { myh1 = (int)__popcll(b1); myh2 = (int)__popcll(b2); }
        }
        h1[blockIdx.x * NEXP + lane] = myh1;
        h2[blockIdx.x * NEXP + lane] = myh2;
        pack[tok0 + lane] = (uint32_t)i1 | ((uint32_t)i2 << 6) |
                            ((uint32_t)r1 << 12) | ((uint32_t)r2 << 18);
    }
}

// ---------------------------------------------------------------------------
// K2: per-expert exclusive scan over the 1024 group histograms, ce totals,
// me reduction, me*ce partial (no atomics). One block per expert.
// ---------------------------------------------------------------------------
__global__ __launch_bounds__(256) void k2_scan(
    const int* __restrict__ h1, const int* __restrict__ h2, const float* __restrict__ mep,
    int* __restrict__ off1, int* __restrict__ off2, int* __restrict__ ce,
    float* __restrict__ mece)
{
    const int e = blockIdx.x, t = threadIdx.x;
    __shared__ int   sb[256];
    __shared__ float fb[256];

    // ---- scan h1
    int v0 = h1[(4 * t + 0) * NEXP + e], v1 = h1[(4 * t + 1) * NEXP + e];
    int v2 = h1[(4 * t + 2) * NEXP + e], v3 = h1[(4 * t + 3) * NEXP + e];
    int ts = v0 + v1 + v2 + v3;
    sb[t] = ts; __syncthreads();
    for (int d = 1; d < 256; d <<= 1) {
        int a = (t >= d) ? sb[t - d] : 0;
        __syncthreads();
        sb[t] += a;
        __syncthreads();
    }
    const int total1 = sb[255];
    int ex = sb[t] - ts;
    off1[(4 * t + 0) * NEXP + e] = ex;
    off1[(4 * t + 1) * NEXP + e] = ex + v0;
    off1[(4 * t + 2) * NEXP + e] = ex + v0 + v1;
    off1[(4 * t + 3) * NEXP + e] = ex + v0 + v1 + v2;
    if (t == 0) ce[e] = total1;
    __syncthreads();

    // ---- scan h2
    v0 = h2[(4 * t + 0) * NEXP + e]; v1 = h2[(4 * t + 1) * NEXP + e];
    v2 = h2[(4 * t + 2) * NEXP + e]; v3 = h2[(4 * t + 3) * NEXP + e];
    ts = v0 + v1 + v2 + v3;
    sb[t] = ts; __syncthreads();
    for (int d = 1; d < 256; d <<= 1) {
        int a = (t >= d) ? sb[t - d] : 0;
        __syncthreads();
        sb[t] += a;
        __syncthreads();
    }
    ex = sb[t] - ts;
    off2[(4 * t + 0) * NEXP + e] = ex;
    off2[(4 * t + 1) * NEXP + e] = ex + v0;
    off2[(4 * t + 2) * NEXP + e] = ex + v0 + v1;
    off2[(4 * t + 3) * NEXP + e] = ex + v0 + v1 + v2;
    __syncthreads();

    // ---- me reduce + me*ce partial (k3 block 0 finishes the 64-way sum)
    float ms = mep[(4 * t + 0) * NEXP + e] + mep[(4 * t + 1) * NEXP + e] +
               mep[(4 * t + 2) * NEXP + e] + mep[(4 * t + 3) * NEXP + e];
    fb[t] = ms; __syncthreads();
    for (int d = 128; d > 0; d >>= 1) {
        if (t < d) fb[t] += fb[t + d];
        __syncthreads();
    }
    if (t == 0) mece[e] = fb[0] * (float)total1;
}

// ---------------------------------------------------------------------------
// K3: final locations + loss (shuffle-reduce of mece by block 0 / wave 0).
// ---------------------------------------------------------------------------
__global__ __launch_bounds__(256) void k3_loc(
    const uint32_t* __restrict__ pack, const int* __restrict__ off1,
    const int* __restrict__ off2, const int* __restrict__ ce,
    const float* __restrict__ mece, float* __restrict__ out)
{
    const int sIdx = blockIdx.x * 256 + threadIdx.x;
    const uint32_t p = pack[sIdx];
    const int i1 = p & 63, i2 = (p >> 6) & 63, r1 = (p >> 12) & 63, r2 = (p >> 18) & 63;
    const int g = sIdx >> 6;
    out[1 + 4 * TOKENS + sIdx] = (float)(off1[g * NEXP + i1] + r1);
    out[1 + 5 * TOKENS + sIdx] = (float)(off2[g * NEXP + i2] + r2 + ce[i2]);

    if (blockIdx.x == 0 && threadIdx.x < 64) {
        float v = mece[threadIdx.x];
#pragma unroll
        for (int d = 32; d > 0; d >>= 1) v += __shfl_down(v, d, 64);
        if (threadIdx.x == 0) out[0] = v * 1.4901161193847656e-08f;  // * E/S^2
    }
}

extern "C" void kernel_launch(void* const* d_in, const int* in_sizes, int n_in,
                              void* d_out, int out_size, void* d_ws, size_t ws_size,
                              hipStream_t stream)
{
    const float* x  = (const float*)d_in[0];   // [65536,1024] fp32
    const float* wg = (const float*)d_in[1];   // [64,1024] fp32
    float* out = (float*)d_out;

    // workspace carve (~1.6 MB)
    char* w = (char*)d_ws;
    uint32_t* pack = (uint32_t*)w; w += (size_t)TOKENS * 4;
    int*   h1   = (int*)w;   w += (size_t)NBLK1 * NEXP * 4;
    int*   h2   = (int*)w;   w += (size_t)NBLK1 * NEXP * 4;
    float* mep  = (float*)w; w += (size_t)NBLK1 * NEXP * 4;
    int*   off1 = (int*)w;   w += (size_t)NBLK1 * NEXP * 4;
    int*   off2 = (int*)w;   w += (size_t)NBLK1 * NEXP * 4;
    int*   ce   = (int*)w;   w += 256;
    float* mece = (float*)w; w += 256;

    k1_gate<<<NBLK1, 512, 0, stream>>>(x, wg, out, pack, h1, h2, mep);
    k2_scan<<<NEXP, 256, 0, stream>>>(h1, h2, mep, off1, off2, ce, mece);
    k3_loc<<<TOKENS / 256, 256, 0, stream>>>(pack, off1, off2, ce, mece, out);
}